// Round 1
// baseline (18452.220 us; speedup 1.0000x reference)
//
#include <hip/hip_runtime.h>
#include <stdint.h>

typedef __attribute__((ext_vector_type(4))) float f32x4;
typedef __attribute__((ext_vector_type(8))) short bf16x8;

#define S_LEN 512
#define BATCH 64
#define DIM   1024
#define HSZ   1024
#define G4    4096   // 4*HS
#define K2    2048   // DIM + HS

// ---------- numeric helpers ----------

__device__ __forceinline__ float bf16r(float x) {
    union { float f; uint32_t u; } v; v.f = x;
    v.u = (v.u + 0x7FFFu + ((v.u >> 16) & 1u)) & 0xFFFF0000u;
    return v.f;
}

__device__ __forceinline__ unsigned short bf16bits(float x) {
    union { float f; uint32_t u; } v; v.f = x;
    uint32_t r = v.u + 0x7FFFu + ((v.u >> 16) & 1u);
    return (unsigned short)(r >> 16);
}

// Quantize 8 values (one BFP block, MAN=7) held in registers -> bf16 bit patterns.
// Matches: frexp(maxabs) -> step = 2^(e-1-7); q = rint(x/step)*step; 0 if maxabs==0.
__device__ __forceinline__ void bfp8_quant(const float v[8], unsigned short o[8]) {
    float m = 0.f;
    #pragma unroll
    for (int i = 0; i < 8; ++i) m = fmaxf(m, fabsf(v[i]));
    if (m > 0.f) {
        int e;
        (void)frexpf(m, &e);                 // m = frac * 2^e, frac in [0.5, 1)
        float step = ldexpf(1.0f, e - 8);    // 2^(e-1-MAN)
        #pragma unroll
        for (int i = 0; i < 8; ++i) {
            float q = rintf(v[i] / step) * step;   // exact pow2 division, RNE
            o[i] = bf16bits(q);                    // exact (<=9 significant bits)
        }
    } else {
        #pragma unroll
        for (int i = 0; i < 8; ++i) o[i] = 0;
    }
}

// Quantize an 8-block from global f32 -> global bf16 (16B store).
__device__ __forceinline__ void bfp8_store(const float* __restrict__ src,
                                           unsigned short* __restrict__ dst) {
    float v[8];
    float4 a = ((const float4*)src)[0];
    float4 b = ((const float4*)src)[1];
    v[0]=a.x; v[1]=a.y; v[2]=a.z; v[3]=a.w;
    v[4]=b.x; v[5]=b.y; v[6]=b.z; v[7]=b.w;
    union { unsigned short us[8]; int4 i4; } o;
    bfp8_quant(v, o.us);
    *(int4*)dst = o.i4;
}

// ---------- setup kernels ----------

// Wt[n][k], n in [0,4096), k in [0,2048): k<1024 -> bfp(U[n][k]); else bfp(V[n][k-1024]).
// One thread per 8-block: 4096*2048/8 = 1,048,576 blocks.
__global__ __launch_bounds__(256) void quant_weights(
    const float* __restrict__ U, const float* __restrict__ V,
    unsigned short* __restrict__ Wt)
{
    int blk = blockIdx.x * 256 + threadIdx.x;       // 0 .. 1048575
    int n  = blk >> 8;                              // 256 blocks per output row
    int kb = blk & 255;
    const float* src = (kb < 128) ? (U + (size_t)n * 1024 + kb * 8)
                                  : (V + (size_t)n * 1024 + (kb - 128) * 8);
    bfp8_store(src, Wt + (size_t)n * 2048 + kb * 8);
}

// xh_q[b][0..1023] = bfp(x0[b]), xh_q[b][1024..2047] = bfp(h0[b]); c_ws = c0.
__global__ __launch_bounds__(256) void init_state(
    const float* __restrict__ x0, const float* __restrict__ h0,
    const float* __restrict__ c0,
    unsigned short* __restrict__ xh_q, float* __restrict__ c_ws)
{
    int idx = blockIdx.x * 256 + threadIdx.x;   // 0..16383
    if (idx < 8192) {
        int b = idx >> 7, j0 = (idx & 127) * 8;
        bfp8_store(x0 + (size_t)b * 1024 + j0, xh_q + (size_t)b * 2048 + j0);
    } else {
        int i = idx - 8192;
        int b = i >> 7, j0 = (i & 127) * 8;
        bfp8_store(h0 + (size_t)b * 1024 + j0, xh_q + (size_t)b * 2048 + 1024 + j0);
        const float4* src = (const float4*)(c0 + (size_t)b * 1024 + j0);
        float4* dst = (float4*)(c_ws + (size_t)b * 1024 + j0);
        dst[0] = src[0]; dst[1] = src[1];
    }
}

// ---------- per-step GEMM: gates_raw = xh_q @ Wt^T  (M=64, N=4096, K=2048) ----------

// XOR swizzle (G4): row stride 128B, byte ^= (row&7)<<4. Applied on write AND read.
__device__ __forceinline__ int lds_off(int row, int kbyte) {
    return row * 128 + (kbyte ^ ((row & 7) << 4));
}

__global__ __launch_bounds__(256) void gates_gemm(
    const unsigned short* __restrict__ xh_q,  // [64][2048] bf16
    const unsigned short* __restrict__ Wt,    // [4096][2048] bf16 (row n = output col)
    float* __restrict__ gates)                // [64][4096] f32
{
    __shared__ char As[64 * 128];
    __shared__ char Bs[64 * 128];
    const int tid = threadIdx.x;
    const int n0 = blockIdx.x * 64;
    const int lane = tid & 63;
    const int wid = tid >> 6;
    const int wm = wid >> 1, wn = wid & 1;     // 2x2 waves over (M, N)
    const int lr = lane & 15, lg = lane >> 4;

    f32x4 acc00 = {0.f,0.f,0.f,0.f}, acc01 = {0.f,0.f,0.f,0.f};
    f32x4 acc10 = {0.f,0.f,0.f,0.f}, acc11 = {0.f,0.f,0.f,0.f};

    for (int it = 0; it < 32; ++it) {          // K = 2048, BK = 64
        const int kc = it * 64;
        __syncthreads();
        #pragma unroll
        for (int s = 0; s < 2; ++s) {
            int ab   = tid + s * 256;          // 512 8-blocks per tile
            int row  = ab >> 3;
            int kloc = (ab & 7) * 8;
            int4 va = *(const int4*)(xh_q + (size_t)row * 2048 + kc + kloc);
            *(int4*)(As + lds_off(row, kloc * 2)) = va;
            int4 vb = *(const int4*)(Wt + (size_t)(n0 + row) * 2048 + kc + kloc);
            *(int4*)(Bs + lds_off(row, kloc * 2)) = vb;
        }
        __syncthreads();
        #pragma unroll
        for (int kk = 0; kk < 2; ++kk) {
            int kb = kk * 64 + lg * 16;        // byte offset of this lane-group's 8 k's
            bf16x8 a0 = *(const bf16x8*)(As + lds_off(wm * 32 + lr,      kb));
            bf16x8 a1 = *(const bf16x8*)(As + lds_off(wm * 32 + 16 + lr, kb));
            bf16x8 b0 = *(const bf16x8*)(Bs + lds_off(wn * 32 + lr,      kb));
            bf16x8 b1 = *(const bf16x8*)(Bs + lds_off(wn * 32 + 16 + lr, kb));
            acc00 = __builtin_amdgcn_mfma_f32_16x16x32_bf16(a0, b0, acc00, 0, 0, 0);
            acc01 = __builtin_amdgcn_mfma_f32_16x16x32_bf16(a0, b1, acc01, 0, 0, 0);
            acc10 = __builtin_amdgcn_mfma_f32_16x16x32_bf16(a1, b0, acc10, 0, 0, 0);
            acc11 = __builtin_amdgcn_mfma_f32_16x16x32_bf16(a1, b1, acc11, 0, 0, 0);
        }
    }

    // C/D layout (verified m89): col = lane&15, row = (lane>>4)*4 + reg
    #pragma unroll
    for (int mi = 0; mi < 2; ++mi) {
        #pragma unroll
        for (int ni = 0; ni < 2; ++ni) {
            f32x4 a;
            if      (mi == 0 && ni == 0) a = acc00;
            else if (mi == 0 && ni == 1) a = acc01;
            else if (mi == 1 && ni == 0) a = acc10;
            else                         a = acc11;
            int grow = wm * 32 + mi * 16 + lg * 4;
            int gcol = n0 + wn * 32 + ni * 16 + lr;
            #pragma unroll
            for (int r = 0; r < 4; ++r)
                gates[(size_t)(grow + r) * 4096 + gcol] = a[r];
        }
    }
}

// ---------- per-step epilogue: activations + state update + re-quantize ----------

__global__ __launch_bounds__(256) void lstm_epilogue(
    const float* __restrict__ gates,     // [64][4096] raw (no bias)
    const float* __restrict__ bih,
    const float* __restrict__ bhh,
    float* __restrict__ c_ws,            // [64][1024] f32, updated in place
    unsigned short* __restrict__ xh_q,   // [64][2048] bf16, refilled for next step
    const float* __restrict__ x_next,    // [64][1024] f32 (unused when last)
    float* __restrict__ out_t,           // [64][1024]
    float* __restrict__ hT,
    float* __restrict__ cT,
    int last)
{
    int idx = blockIdx.x * 256 + threadIdx.x;  // 0..8191, one 8-block of h each
    int b = idx >> 7;
    int j0 = (idx & 127) * 8;
    const float* gr = gates + (size_t)b * 4096;
    const float* cr = c_ws + (size_t)b * 1024 + j0;

    float h8[8], c8[8];
    #pragma unroll
    for (int e = 0; e < 8; ++e) {
        int j = j0 + e;
        // b_q = bf16(bih) + bf16(bhh); gate = bf16(raw + b_q)
        float bq_i = bf16r(bih[j])        + bf16r(bhh[j]);
        float bq_f = bf16r(bih[1024 + j]) + bf16r(bhh[1024 + j]);
        float bq_g = bf16r(bih[2048 + j]) + bf16r(bhh[2048 + j]);
        float bq_o = bf16r(bih[3072 + j]) + bf16r(bhh[3072 + j]);
        float gi = bf16r(gr[j]        + bq_i);
        float gf = bf16r(gr[1024 + j] + bq_f);
        float gg = bf16r(gr[2048 + j] + bq_g);
        float go = bf16r(gr[3072 + j] + bq_o);

        float i_t = bf16r(1.f / (1.f + expf(-gi)));
        float f_t = bf16r(1.f / (1.f + expf(-gf)));
        float g_t = bf16r(tanhf(gg));
        float o_t = bf16r(1.f / (1.f + expf(-go)));

        // c = bf16(f*c + i*g): IEEE mul/add, no fma contraction (match np assoc)
        float p1 = __fmul_rn(f_t, cr[e]);
        float p2 = __fmul_rn(i_t, g_t);
        float cn = bf16r(__fadd_rn(p1, p2));
        float hn = bf16r(__fmul_rn(o_t, tanhf(cn)));
        c8[e] = cn; h8[e] = hn;
    }

    // stores: out[t], c
    {
        float4* po = (float4*)(out_t + (size_t)b * 1024 + j0);
        float4* pc = (float4*)(c_ws + (size_t)b * 1024 + j0);
        float4 h0v = {h8[0], h8[1], h8[2], h8[3]};
        float4 h1v = {h8[4], h8[5], h8[6], h8[7]};
        float4 c0v = {c8[0], c8[1], c8[2], c8[3]};
        float4 c1v = {c8[4], c8[5], c8[6], c8[7]};
        po[0] = h0v; po[1] = h1v;
        pc[0] = c0v; pc[1] = c1v;
        if (last) {
            float4* ph = (float4*)(hT + (size_t)b * 1024 + j0);
            float4* pq = (float4*)(cT + (size_t)b * 1024 + j0);
            ph[0] = h0v; ph[1] = h1v;
            pq[0] = c0v; pq[1] = c1v;
        }
    }

    // re-quantize h for next step (bfp blocks of 8 along hidden dim)
    {
        union { unsigned short us[8]; int4 i4; } o;
        bfp8_quant(h8, o.us);
        *(int4*)(xh_q + (size_t)b * 2048 + 1024 + j0) = o.i4;
    }
    // pre-quantize x_{t+1} for next step
    if (!last) {
        bfp8_store(x_next + (size_t)b * 1024 + j0, xh_q + (size_t)b * 2048 + j0);
    }
}

// ---------- launcher ----------

extern "C" void kernel_launch(void* const* d_in, const int* in_sizes, int n_in,
                              void* d_out, int out_size, void* d_ws, size_t ws_size,
                              hipStream_t stream) {
    const float* x   = (const float*)d_in[0];  // [512][64][1024]
    const float* h0  = (const float*)d_in[1];  // [64][1024]
    const float* c0  = (const float*)d_in[2];  // [64][1024]
    const float* U   = (const float*)d_in[3];  // [4096][1024]
    const float* V   = (const float*)d_in[4];  // [4096][1024]
    const float* bih = (const float*)d_in[5];  // [4096]
    const float* bhh = (const float*)d_in[6];  // [4096]

    float* out = (float*)d_out;                           // [512][64][1024]
    float* hT  = out + (size_t)S_LEN * BATCH * HSZ;       // [64][1024]
    float* cT  = hT + (size_t)BATCH * HSZ;                // [64][1024]

    char* ws = (char*)d_ws;
    unsigned short* Wt   = (unsigned short*)ws;                    // 4096*2048*2 = 16 MB
    ws += (size_t)G4 * K2 * 2;
    unsigned short* xh_q = (unsigned short*)ws;                    // 64*2048*2 = 256 KB
    ws += (size_t)BATCH * K2 * 2;
    float* c_ws = (float*)ws;                                      // 64*1024*4 = 256 KB
    ws += (size_t)BATCH * HSZ * 4;
    float* gates = (float*)ws;                                     // 64*4096*4 = 1 MB
    ws += (size_t)BATCH * G4 * 4;

    hipLaunchKernelGGL(quant_weights, dim3(4096), dim3(256), 0, stream, U, V, Wt);
    hipLaunchKernelGGL(init_state, dim3(64), dim3(256), 0, stream, x, h0, c0, xh_q, c_ws);

    for (int t = 0; t < S_LEN; ++t) {
        hipLaunchKernelGGL(gates_gemm, dim3(64), dim3(256), 0, stream, xh_q, Wt, gates);
        int last = (t == S_LEN - 1);
        const float* x_next = last ? x : (x + (size_t)(t + 1) * BATCH * DIM);
        hipLaunchKernelGGL(lstm_epilogue, dim3(32), dim3(256), 0, stream,
                           gates, bih, bhh, c_ws, xh_q, x_next,
                           out + (size_t)t * BATCH * HSZ, hT, cT, last);
    }
}

// Round 2
// 14496.971 us; speedup vs baseline: 1.2728x; 1.2728x over previous
//
#include <hip/hip_runtime.h>
#include <stdint.h>

typedef __attribute__((ext_vector_type(4))) float f32x4;
typedef __attribute__((ext_vector_type(8))) short bf16x8;

#define S_LEN 512
#define BATCH 64
#define DIM   1024
#define HSZ   1024
#define G4    4096

// ---------- numeric helpers ----------

__device__ __forceinline__ float bf16r(float x) {
    union { float f; uint32_t u; } v; v.f = x;
    v.u = (v.u + 0x7FFFu + ((v.u >> 16) & 1u)) & 0xFFFF0000u;
    return v.f;
}

__device__ __forceinline__ unsigned short bf16bits(float x) {
    union { float f; uint32_t u; } v; v.f = x;
    uint32_t r = v.u + 0x7FFFu + ((v.u >> 16) & 1u);
    return (unsigned short)(r >> 16);
}

// BFP block of 8, MAN=7: step = 2^(floor(log2(max|v|)) - 7); q = rint(v/step)*step.
// Every q is exactly representable in bf16 (<= 9 significant bits).
__device__ __forceinline__ void bfp8_quant(const float v[8], unsigned short o[8]) {
    float m = 0.f;
    #pragma unroll
    for (int i = 0; i < 8; ++i) m = fmaxf(m, fabsf(v[i]));
    if (m > 0.f) {
        int e;
        (void)frexpf(m, &e);
        float step = ldexpf(1.0f, e - 8);
        #pragma unroll
        for (int i = 0; i < 8; ++i) {
            float q = rintf(v[i] / step) * step;
            o[i] = bf16bits(q);
        }
    } else {
        #pragma unroll
        for (int i = 0; i < 8; ++i) o[i] = 0;
    }
}

__device__ __forceinline__ void bfp8_store(const float* __restrict__ src,
                                           unsigned short* __restrict__ dst) {
    float v[8];
    float4 a = ((const float4*)src)[0];
    float4 b = ((const float4*)src)[1];
    v[0]=a.x; v[1]=a.y; v[2]=a.z; v[3]=a.w;
    v[4]=b.x; v[5]=b.y; v[6]=b.z; v[7]=b.w;
    union { unsigned short us[8]; int4 i4; } o;
    bfp8_quant(v, o.us);
    *(int4*)dst = o.i4;
}

// ---------- setup kernels ----------

// Ug[n][k] = bfp(U[n][k]); Vp[gc][cc][k] = bfp(V[q*1024 + gc*16 + jj][k]) with cc = q*16+jj.
// Also bq[n] = bf16(bih)+bf16(bhh).
__global__ __launch_bounds__(256) void quant_weights_pack(
    const float* __restrict__ U, const float* __restrict__ V,
    unsigned short* __restrict__ Ug, unsigned short* __restrict__ Vp,
    const float* __restrict__ bih, const float* __restrict__ bhh,
    float* __restrict__ bq)
{
    int blk = blockIdx.x * 256 + threadIdx.x;   // 0 .. 1048575
    if (blk < 524288) {
        int n = blk >> 7, kb = blk & 127;
        bfp8_store(U + (size_t)n * 1024 + kb * 8, Ug + (size_t)n * 1024 + kb * 8);
    } else {
        int i = blk - 524288;
        int n = i >> 7, kb = i & 127;
        int q = n >> 10, j = n & 1023;
        int gc = j >> 4, cc = (q << 4) | (j & 15);
        bfp8_store(V + (size_t)n * 1024 + kb * 8,
                   Vp + ((size_t)gc * 64 + cc) * 1024 + kb * 8);
    }
    if (blk < 4096) bq[blk] = bf16r(bih[blk]) + bf16r(bhh[blk]);
}

// hq0 = bfp(h0) along hidden dim; c_ws = c0 (raw f32).
__global__ __launch_bounds__(256) void init_state(
    const float* __restrict__ h0, const float* __restrict__ c0,
    unsigned short* __restrict__ hq0, float* __restrict__ c_ws)
{
    int idx = blockIdx.x * 256 + threadIdx.x;   // 0..8191
    int b = idx >> 7, j0 = (idx & 127) * 8;
    bfp8_store(h0 + (size_t)b * 1024 + j0, hq0 + (size_t)b * 1024 + j0);
    const float4* src = (const float4*)(c0 + (size_t)b * 1024 + j0);
    float4* dst = (float4*)(c_ws + (size_t)b * 1024 + j0);
    dst[0] = src[0]; dst[1] = src[1];
}

// Quantize a chunk of x: rows = TC*64, each row 1024 -> 128 blocks of 8.
__global__ __launch_bounds__(256) void quant_x(
    const float* __restrict__ xc, unsigned short* __restrict__ Xq)
{
    int blk = blockIdx.x * 256 + threadIdx.x;
    int r = blk >> 7, j0 = (blk & 127) * 8;
    bfp8_store(xc + (size_t)r * 1024 + j0, Xq + (size_t)r * 1024 + j0);
}

// ---------- phase 1: Gx = Xq @ Ug^T + bq   (M = rows, N = 4096, K = 1024) ----------
// 128x128 tile, BK=64, 4 waves 2x2, reg-prefetch + double-buffered XOR-swizzled LDS.

__global__ __launch_bounds__(256) void gemm_xu(
    const unsigned short* __restrict__ Xq,   // [M][1024]
    const unsigned short* __restrict__ Ug,   // [4096][1024]
    const float* __restrict__ bq,            // [4096]
    float* __restrict__ Gx)                  // [M][4096]
{
    __shared__ char As[2][128 * 128];
    __shared__ char Bs[2][128 * 128];
    const int tid = threadIdx.x;
    const int m0 = blockIdx.x * 128;
    const int n0 = blockIdx.y * 128;
    const int lane = tid & 63, wid = tid >> 6;
    const int wm = wid >> 1, wn = wid & 1;
    const int lr = lane & 15, lg = lane >> 4;
    const int srow = tid >> 3, skb = tid & 7;

    f32x4 acc[4][4];
    #pragma unroll
    for (int i = 0; i < 4; ++i)
        #pragma unroll
        for (int j = 0; j < 4; ++j) acc[i][j] = (f32x4){0.f,0.f,0.f,0.f};

    int4 pa[4], pb[4];
    auto load = [&](int it) {
        int kc = it * 64 + skb * 8;
        #pragma unroll
        for (int i = 0; i < 4; ++i) {
            pa[i] = *(const int4*)(Xq + (size_t)(m0 + srow + i * 32) * 1024 + kc);
            pb[i] = *(const int4*)(Ug + (size_t)(n0 + srow + i * 32) * 1024 + kc);
        }
    };
    auto store = [&](int buf) {
        #pragma unroll
        for (int i = 0; i < 4; ++i) {
            int row = srow + i * 32;
            int off = row * 128 + ((skb * 16) ^ ((row & 7) << 4));
            *(int4*)(As[buf] + off) = pa[i];
            *(int4*)(Bs[buf] + off) = pb[i];
        }
    };

    load(0); store(0);
    for (int it = 0; it < 16; ++it) {
        __syncthreads();
        int cur = it & 1;
        if (it < 15) load(it + 1);
        #pragma unroll
        for (int kk = 0; kk < 2; ++kk) {
            bf16x8 af[4], bfr[4];
            #pragma unroll
            for (int mi = 0; mi < 4; ++mi) {
                int row = wm * 64 + mi * 16 + lr;
                af[mi] = *(const bf16x8*)(As[cur] + row * 128 + ((kk * 64 + lg * 16) ^ ((row & 7) << 4)));
            }
            #pragma unroll
            for (int ni = 0; ni < 4; ++ni) {
                int row = wn * 64 + ni * 16 + lr;
                bfr[ni] = *(const bf16x8*)(Bs[cur] + row * 128 + ((kk * 64 + lg * 16) ^ ((row & 7) << 4)));
            }
            #pragma unroll
            for (int mi = 0; mi < 4; ++mi)
                #pragma unroll
                for (int ni = 0; ni < 4; ++ni)
                    acc[mi][ni] = __builtin_amdgcn_mfma_f32_16x16x32_bf16(af[mi], bfr[ni], acc[mi][ni], 0, 0, 0);
        }
        if (it < 15) store(cur ^ 1);
    }

    #pragma unroll
    for (int mi = 0; mi < 4; ++mi) {
        int grow = m0 + wm * 64 + mi * 16 + lg * 4;
        #pragma unroll
        for (int ni = 0; ni < 4; ++ni) {
            int gcol = n0 + wn * 64 + ni * 16 + lr;
            float bqv = bq[gcol];
            #pragma unroll
            for (int r = 0; r < 4; ++r)
                Gx[(size_t)(grow + r) * 4096 + gcol] = acc[mi][ni][r] + bqv;
        }
    }
}

// ---------- fused sequential step ----------
// 128 wgs: g = (msel, gc). Tile M=32 (rows msel*32..), N=64 (4 gates x 16 h-cols of gc), K=1024.
// acc init = Gxt (x@U + bq). Epilogue: activations -> LDS -> c/h update -> out, h requantize.

__global__ __launch_bounds__(256) void lstm_step(
    const unsigned short* __restrict__ hq_in,   // [64][1024]
    const unsigned short* __restrict__ Vp,      // [64][64][1024]
    const float* __restrict__ Gxt,              // [64][4096] (bias included)
    float* __restrict__ c_ws,                   // [64][1024]
    unsigned short* __restrict__ hq_out,        // [64][1024]
    float* __restrict__ out_t,                  // [64][1024]
    float* __restrict__ hT, float* __restrict__ cT, int last)
{
    __shared__ char As[2][32 * 256];
    __shared__ char Bs[2][64 * 256];
    __shared__ float gbuf[32][68];
    const int tid = threadIdx.x;
    const int g = blockIdx.x;
    const int msel = g >> 6, gc = g & 63;
    const int lane = tid & 63, wid = tid >> 6;
    const int wm = wid >> 1, wn = wid & 1;
    const int lr = lane & 15, lg = lane >> 4;
    const int srow = tid >> 4, skb = tid & 15;

    // acc init from precomputed x-part (+bias)
    f32x4 acc[2];
    #pragma unroll
    for (int nt = 0; nt < 2; ++nt) {
        int cc = wn * 32 + nt * 16 + lr;
        int n = ((cc >> 4) << 10) + gc * 16 + (cc & 15);
        #pragma unroll
        for (int r = 0; r < 4; ++r)
            acc[nt][r] = Gxt[(size_t)(msel * 32 + wm * 16 + lg * 4 + r) * 4096 + n];
    }

    const unsigned short* Vg = Vp + (size_t)gc * 64 * 1024;

    int4 pa[2], pb[4];
    auto load = [&](int it) {
        int kc = it * 128 + skb * 8;
        #pragma unroll
        for (int i = 0; i < 2; ++i)
            pa[i] = *(const int4*)(hq_in + (size_t)(msel * 32 + srow + i * 16) * 1024 + kc);
        #pragma unroll
        for (int i = 0; i < 4; ++i)
            pb[i] = *(const int4*)(Vg + (size_t)(srow + i * 16) * 1024 + kc);
    };
    auto store = [&](int buf) {
        #pragma unroll
        for (int i = 0; i < 2; ++i) {
            int row = srow + i * 16;
            *(int4*)(As[buf] + row * 256 + ((skb * 16) ^ ((row & 15) << 4))) = pa[i];
        }
        #pragma unroll
        for (int i = 0; i < 4; ++i) {
            int row = srow + i * 16;
            *(int4*)(Bs[buf] + row * 256 + ((skb * 16) ^ ((row & 15) << 4))) = pb[i];
        }
    };

    load(0); store(0);
    for (int it = 0; it < 8; ++it) {
        __syncthreads();
        int cur = it & 1;
        if (it < 7) load(it + 1);
        #pragma unroll
        for (int kk = 0; kk < 4; ++kk) {
            int arow = wm * 16 + lr;
            bf16x8 a = *(const bf16x8*)(As[cur] + arow * 256 + ((kk * 64 + lg * 16) ^ ((arow & 15) << 4)));
            #pragma unroll
            for (int nt = 0; nt < 2; ++nt) {
                int brow = wn * 32 + nt * 16 + lr;
                bf16x8 b = *(const bf16x8*)(Bs[cur] + brow * 256 + ((kk * 64 + lg * 16) ^ ((brow & 15) << 4)));
                acc[nt] = __builtin_amdgcn_mfma_f32_16x16x32_bf16(a, b, acc[nt], 0, 0, 0);
            }
        }
        if (it < 7) store(cur ^ 1);
    }

    // activations (gate tile q is uniform per acc tile: q = wn*2 + nt)
    #pragma unroll
    for (int nt = 0; nt < 2; ++nt) {
        int q = wn * 2 + nt;
        int cc = wn * 32 + nt * 16 + lr;
        #pragma unroll
        for (int r = 0; r < 4; ++r) {
            float gate = bf16r(acc[nt][r]);
            float act = (q == 2) ? bf16r(tanhf(gate))
                                 : bf16r(1.f / (1.f + expf(-gate)));
            gbuf[wm * 16 + lg * 4 + r][cc] = act;
        }
    }
    __syncthreads();

    // c/h update: 64 threads, one 8-block each
    if (tid < 64) {
        int b = tid >> 1, blk = tid & 1;
        int bg = msel * 32 + b;
        int j0 = gc * 16 + blk * 8;
        float h8[8], c8[8];
        const float* cw = c_ws + (size_t)bg * 1024 + j0;
        #pragma unroll
        for (int e = 0; e < 8; ++e) {
            int jl = blk * 8 + e;
            float i_t = gbuf[b][jl];
            float f_t = gbuf[b][jl + 16];
            float g_t = gbuf[b][jl + 32];
            float o_t = gbuf[b][jl + 48];
            float cn = bf16r(__fadd_rn(__fmul_rn(f_t, cw[e]), __fmul_rn(i_t, g_t)));
            float hn = bf16r(__fmul_rn(o_t, tanhf(cn)));
            c8[e] = cn; h8[e] = hn;
        }
        float4 c0v = {c8[0],c8[1],c8[2],c8[3]}, c1v = {c8[4],c8[5],c8[6],c8[7]};
        float4 h0v = {h8[0],h8[1],h8[2],h8[3]}, h1v = {h8[4],h8[5],h8[6],h8[7]};
        float4* pc = (float4*)(c_ws + (size_t)bg * 1024 + j0);
        pc[0] = c0v; pc[1] = c1v;
        float4* po = (float4*)(out_t + (size_t)bg * 1024 + j0);
        po[0] = h0v; po[1] = h1v;
        if (last) {
            float4* ph = (float4*)(hT + (size_t)bg * 1024 + j0);
            float4* pq = (float4*)(cT + (size_t)bg * 1024 + j0);
            ph[0] = h0v; ph[1] = h1v;
            pq[0] = c0v; pq[1] = c1v;
        }
        union { unsigned short us[8]; int4 i4; } o;
        bfp8_quant(h8, o.us);
        *(int4*)(hq_out + (size_t)bg * 1024 + j0) = o.i4;
    }
}

// ---------- launcher ----------

extern "C" void kernel_launch(void* const* d_in, const int* in_sizes, int n_in,
                              void* d_out, int out_size, void* d_ws, size_t ws_size,
                              hipStream_t stream) {
    const float* x   = (const float*)d_in[0];
    const float* h0  = (const float*)d_in[1];
    const float* c0  = (const float*)d_in[2];
    const float* U   = (const float*)d_in[3];
    const float* V   = (const float*)d_in[4];
    const float* bih = (const float*)d_in[5];
    const float* bhh = (const float*)d_in[6];

    float* out = (float*)d_out;
    float* hT  = out + (size_t)S_LEN * BATCH * HSZ;
    float* cT  = hT + (size_t)BATCH * HSZ;

    char* p = (char*)d_ws;
    unsigned short* Ug = (unsigned short*)p; p += (size_t)G4 * 1024 * 2;   // 8 MB
    unsigned short* Vp = (unsigned short*)p; p += (size_t)G4 * 1024 * 2;   // 8 MB
    float* bq = (float*)p;                   p += (size_t)G4 * 4;          // 16 KB
    unsigned short* hq0 = (unsigned short*)p; p += (size_t)BATCH * HSZ * 2;
    unsigned short* hq1 = (unsigned short*)p; p += (size_t)BATCH * HSZ * 2;
    float* c_ws = (float*)p;                 p += (size_t)BATCH * HSZ * 4;
    size_t fixed = (size_t)(p - (char*)d_ws);

    int TC = 512;
    while (TC > 2 && fixed + (size_t)TC * 64 * 1024 * 2 + (size_t)TC * 64 * 4096 * 4 > ws_size)
        TC >>= 1;
    unsigned short* Xq = (unsigned short*)p; p += (size_t)TC * 64 * 1024 * 2;
    float* Gx = (float*)p;

    unsigned short* hq[2] = { hq0, hq1 };

    hipLaunchKernelGGL(quant_weights_pack, dim3(4096), dim3(256), 0, stream,
                       U, V, Ug, Vp, bih, bhh, bq);
    hipLaunchKernelGGL(init_state, dim3(32), dim3(256), 0, stream, h0, c0, hq[0], c_ws);

    int t = 0;
    for (int t0 = 0; t0 < S_LEN; t0 += TC) {
        int rows = TC * 64;
        hipLaunchKernelGGL(quant_x, dim3(rows / 2), dim3(256), 0, stream,
                           x + (size_t)t0 * BATCH * DIM, Xq);
        hipLaunchKernelGGL(gemm_xu, dim3(rows / 128, 32), dim3(256), 0, stream,
                           Xq, Ug, bq, Gx);
        for (int tl = 0; tl < TC; ++tl, ++t) {
            int last = (t == S_LEN - 1);
            hipLaunchKernelGGL(lstm_step, dim3(128), dim3(256), 0, stream,
                               hq[t & 1], Vp, Gx + (size_t)tl * BATCH * G4, c_ws,
                               hq[(t + 1) & 1], out + (size_t)t * BATCH * HSZ,
                               hT, cT, last);
        }
    }
}